// Round 9
// baseline (266.275 us; speedup 1.0000x reference)
//
#include <hip/hip_runtime.h>
#include <hip/hip_bf16.h>
#include <cstdint>
#include <cstddef>

#define B_ 2
#define T_ 2048
#define C_ 1024
#define H_ 16
#define D_ 64
#define BT_ (B_*T_)
#define QKV_S 3072

typedef __bf16 bf16;
typedef __bf16 bf16x4 __attribute__((ext_vector_type(4)));
typedef __bf16 bf16x8 __attribute__((ext_vector_type(8)));
typedef float f32x4 __attribute__((ext_vector_type(4)));

// ---------------------------------------------------------------- fused cast f32->bf16 (+ bias concat)
__global__ __launch_bounds__(256) void cast_all(const float* __restrict__ x,
                                                const float* __restrict__ wq,
                                                const float* __restrict__ wk,
                                                const float* __restrict__ wv,
                                                const float* __restrict__ wo,
                                                const float* __restrict__ bq,
                                                const float* __restrict__ bk,
                                                const float* __restrict__ bv,
                                                bf16* __restrict__ xb,
                                                bf16* __restrict__ wqkvb,
                                                bf16* __restrict__ wob,
                                                float* __restrict__ bqkv) {
  const int X4 = (BT_ * C_) / 4;     // 1048576
  const int W4 = (C_ * C_) / 4;      // 262144
  int i = blockIdx.x * blockDim.x + threadIdx.x;
  if (i >= X4 + 4 * W4 + 768) return;
  if (i >= X4 + 4 * W4) {
    int idx = i - (X4 + 4 * W4);        // 0..767 float4s
    int w = idx >> 8, off = idx & 255;
    const float* src = (w == 0) ? bq : (w == 1) ? bk : bv;
    reinterpret_cast<float4*>(bqkv + w * C_)[off] = reinterpret_cast<const float4*>(src)[off];
    return;
  }
  const float* src;
  bf16* dst;
  int off;
  if (i < X4) {
    src = x; dst = xb; off = i;
  } else {
    int k = i - X4;
    int w = k >> 18;        // /W4
    off = k & (W4 - 1);
    src = (w == 0) ? wq : (w == 1) ? wk : (w == 2) ? wv : wo;
    dst = (w < 3) ? (wqkvb + (size_t)w * C_ * C_) : wob;
  }
  float4 v = reinterpret_cast<const float4*>(src)[off];
  bf16x4 o;
  o[0] = (bf16)v.x; o[1] = (bf16)v.y; o[2] = (bf16)v.z; o[3] = (bf16)v.w;
  *reinterpret_cast<bf16x4*>(dst + (size_t)off * 4) = o;
}

// ---------------------------------------------------------------- QKV GEMM: 128x256 tile, swizzled LDS
// A [M,K] bf16, Bm [N,K] bf16, bias [N] f32. BM=128, BN=256, BK=32.
// 4 waves, each a 64x128 wave-tile (4 m-frags x 8 n-frags).
// LDS rows are 64 B (BK=32) -> swizzle must stay inside the row: 4 slots of 16 B,
// byte ^= (row&3)<<4, applied on the inverse-swizzled GLOBAL source (linear
// global_load_lds dest) AND on every fragment read (both-sides-or-neither).
// Reads go from 8-way to <=4-way bank conflicts.
// 3-buffer depth-2 pipeline, counted vmcnt (6 loads/stage -> vmcnt(6)), one raw barrier/step.
// FUSE_VT: n0 >= 2048 blocks write output transposed to VtOut[bh][d][t].
template<typename OutT, bool FUSE_VT>
__global__ __launch_bounds__(256) void gemm_qkv(const bf16* __restrict__ A,
                                                const bf16* __restrict__ Bm,
                                                const float* __restrict__ bias,
                                                OutT* __restrict__ Cout,
                                                bf16* __restrict__ VtOut,
                                                int M, int N, int K) {
  __shared__ bf16 As[3][128 * 32];   // 24 KB
  __shared__ bf16 Bs[3][256 * 32];   // 48 KB
  const int tid = threadIdx.x;
  const int wid = tid >> 6, lane = tid & 63;
  const int grp = lane >> 4, li = lane & 15;
  const int wr = wid >> 1, wc = wid & 1;          // 2M x 2N waves
  const int m0 = blockIdx.y * 128, n0 = blockIdx.x * 256;

  f32x4 acc[4][8] = {};

  // staging: thread covers row (p*64 + wid*16 + rl), 16B at inverse-swizzled source col
  const int rl = lane >> 2;                                       // 0..15; row&3 == rl&3
  const int soff = ((((lane & 3) * 16) ^ ((rl & 3) << 4)) >> 1);  // elem offset, < 32

  auto stage = [&](int k0, int bufi) __attribute__((always_inline)) {
#pragma unroll
    for (int p = 0; p < 2; ++p) {
      const bf16* ga = A + (size_t)(m0 + p * 64 + wid * 16 + rl) * K + k0 + soff;
      __builtin_amdgcn_global_load_lds((__attribute__((address_space(1))) void*)ga,
                                       (__attribute__((address_space(3))) void*)(&As[bufi][p * 2048 + wid * 512]), 16, 0, 0);
    }
#pragma unroll
    for (int p = 0; p < 4; ++p) {
      const bf16* gb = Bm + (size_t)(n0 + p * 64 + wid * 16 + rl) * K + k0 + soff;
      __builtin_amdgcn_global_load_lds((__attribute__((address_space(1))) void*)gb,
                                       (__attribute__((address_space(3))) void*)(&Bs[bufi][p * 2048 + wid * 512]), 16, 0, 0);
    }
  };

  const int rdx = ((grp * 8) ^ ((li & 3) << 3));   // swizzled elem col for reads (row&3 == li&3)

  const int nt = K >> 5;
  stage(0, 0);
  stage(32, 1);
  int r = 0;
  for (int t = 0; t < nt; ++t) {
    if (t + 1 < nt) asm volatile("s_waitcnt vmcnt(6)\ns_barrier" ::: "memory");
    else            asm volatile("s_waitcnt vmcnt(0)\ns_barrier" ::: "memory");
    if (t + 2 < nt) stage((t + 2) * 32, (r == 0) ? 2 : r - 1);   // (r+2)%3

    bf16x8 af[4], bfr[8];
#pragma unroll
    for (int m = 0; m < 4; ++m)
      af[m] = *reinterpret_cast<const bf16x8*>(&As[r][(wr * 64 + m * 16 + li) * 32 + rdx]);
#pragma unroll
    for (int n = 0; n < 8; ++n)
      bfr[n] = *reinterpret_cast<const bf16x8*>(&Bs[r][(wc * 128 + n * 16 + li) * 32 + rdx]);
    __builtin_amdgcn_s_setprio(1);
#pragma unroll
    for (int m = 0; m < 4; ++m)
#pragma unroll
      for (int n = 0; n < 8; ++n)
        acc[m][n] = __builtin_amdgcn_mfma_f32_16x16x32_bf16(af[m], bfr[n], acc[m][n], 0, 0, 0);
    __builtin_amdgcn_s_setprio(0);

    r = (r == 2) ? 0 : r + 1;
  }

  float bcol[8];
#pragma unroll
  for (int n = 0; n < 8; ++n) bcol[n] = bias[n0 + wc * 128 + n * 16 + li];

  if (FUSE_VT && n0 >= 2 * C_) {
    // V block: write transposed to Vt[b*16+h][d][t]
#pragma unroll
    for (int m = 0; m < 4; ++m) {
      const int row0 = m0 + wr * 64 + m * 16 + grp * 4;   // 4-aligned
      const int b = row0 >> 11, t = row0 & (T_ - 1);
#pragma unroll
      for (int n = 0; n < 8; ++n) {
        const int hd = (n0 - 2 * C_) + wc * 128 + n * 16 + li;
        bf16x4 o4;
#pragma unroll
        for (int j = 0; j < 4; ++j) o4[j] = (bf16)(acc[m][n][j] + bcol[n]);
        *reinterpret_cast<bf16x4*>(VtOut + ((size_t)(b * C_ + hd)) * T_ + t) = o4;
      }
    }
  } else {
#pragma unroll
    for (int m = 0; m < 4; ++m) {
#pragma unroll
      for (int n = 0; n < 8; ++n) {
        const int col = n0 + wc * 128 + n * 16 + li;
#pragma unroll
        for (int j = 0; j < 4; ++j) {
          const int row = m0 + wr * 64 + m * 16 + grp * 4 + j;
          float v = acc[m][n][j] + bcol[n];
          Cout[(size_t)row * N + col] = (OutT)v;
        }
      }
    }
  }
}

// ---------------------------------------------------------------- out GEMM: 128x128 (unchanged R7)
template<typename OutT>
__global__ __launch_bounds__(256) void gemm_bt(const bf16* __restrict__ A,
                                               const bf16* __restrict__ Bm,
                                               const float* __restrict__ bias,
                                               OutT* __restrict__ Cout,
                                               int M, int N, int K) {
  __shared__ bf16 As[3][128 * 32];
  __shared__ bf16 Bs[3][128 * 32];
  const int tid = threadIdx.x;
  const int wid = tid >> 6, lane = tid & 63;
  const int grp = lane >> 4, li = lane & 15;
  const int wr = wid >> 1, wc = wid & 1;
  const int m0 = blockIdx.y * 128, n0 = blockIdx.x * 128;

  f32x4 acc[4][4] = {};

  const int srow = lane >> 2;         // 0..15
  const int scol = (lane & 3) * 8;    // 0,8,16,24

  auto stage = [&](int k0, int bufi) __attribute__((always_inline)) {
#pragma unroll
    for (int p = 0; p < 2; ++p) {
      const int rbase = (p * 4 + wid) * 16;
      const bf16* ga = A + (size_t)(m0 + rbase + srow) * K + (k0 + scol);
      const bf16* gb = Bm + (size_t)(n0 + rbase + srow) * K + (k0 + scol);
      __builtin_amdgcn_global_load_lds((__attribute__((address_space(1))) void*)ga,
                                       (__attribute__((address_space(3))) void*)(&As[bufi][(p * 4 + wid) * 512]), 16, 0, 0);
      __builtin_amdgcn_global_load_lds((__attribute__((address_space(1))) void*)gb,
                                       (__attribute__((address_space(3))) void*)(&Bs[bufi][(p * 4 + wid) * 512]), 16, 0, 0);
    }
  };

  const int nt = K >> 5;
  stage(0, 0);
  if (nt > 1) stage(32, 1);
  int r = 0;
  for (int t = 0; t < nt; ++t) {
    if (t + 1 < nt) asm volatile("s_waitcnt vmcnt(4)\ns_barrier" ::: "memory");
    else            asm volatile("s_waitcnt vmcnt(0)\ns_barrier" ::: "memory");
    if (t + 2 < nt) stage((t + 2) * 32, (r == 0) ? 2 : r - 1);

    bf16x8 af[4], bfr[4];
#pragma unroll
    for (int m = 0; m < 4; ++m)
      af[m] = *reinterpret_cast<const bf16x8*>(&As[r][(wr * 64 + m * 16 + li) * 32 + grp * 8]);
#pragma unroll
    for (int n = 0; n < 4; ++n)
      bfr[n] = *reinterpret_cast<const bf16x8*>(&Bs[r][(wc * 64 + n * 16 + li) * 32 + grp * 8]);
#pragma unroll
    for (int m = 0; m < 4; ++m)
#pragma unroll
      for (int n = 0; n < 4; ++n)
        acc[m][n] = __builtin_amdgcn_mfma_f32_16x16x32_bf16(af[m], bfr[n], acc[m][n], 0, 0, 0);

    r = (r == 2) ? 0 : r + 1;
  }

  float bcol[4];
#pragma unroll
  for (int n = 0; n < 4; ++n) bcol[n] = bias[n0 + wc * 64 + n * 16 + li];
#pragma unroll
  for (int m = 0; m < 4; ++m) {
#pragma unroll
    for (int n = 0; n < 4; ++n) {
      const int col = n0 + wc * 64 + n * 16 + li;
#pragma unroll
      for (int j = 0; j < 4; ++j) {
        const int row = m0 + wr * 64 + m * 16 + grp * 4 + j;
        float v = acc[m][n][j] + bcol[n];
        Cout[(size_t)row * N + col] = (OutT)v;
      }
    }
  }
}

// ---------------------------------------------------------------- flash attention w/ ALiBi (unchanged R7)
__global__ __launch_bounds__(512) void attn_kernel(const bf16* __restrict__ qkv,
                                                   const bf16* __restrict__ Vt,
                                                   bf16* __restrict__ Y) {
  __shared__ bf16 Ks[3][64 * 64];
  __shared__ bf16 Vs[3][64 * 64];
  __shared__ bf16 Ps[8 * 16 * 72];

  const int tid = threadIdx.x;
  const int wid = tid >> 6, lane = tid & 63;
  const int grp = lane >> 4, li = lane & 15;
  const int QT = gridDim.x - 1 - blockIdx.x;
  const int bh = blockIdx.y;
  const int b = bh >> 4, h = bh & 15;
  const int q0 = QT * 128;
  const int wq0 = q0 + wid * 16;
  const int qi = wq0 + li;
  const float slope = exp2f(-0.5f * (float)(h + 1));

  bf16* Pw = Ps + wid * (16 * 72);

  bf16x8 qf[2];
  {
    const bf16* qrow = qkv + (size_t)(b * T_ + qi) * QKV_S + h * D_;
    qf[0] = *reinterpret_cast<const bf16x8*>(qrow + grp * 8);
    qf[1] = *reinterpret_cast<const bf16x8*>(qrow + 32 + grp * 8);
#pragma unroll
    for (int c = 0; c < 2; ++c)
#pragma unroll
      for (int j = 0; j < 8; ++j)
        qf[c][j] = (bf16)((float)qf[c][j] * 0.125f);
  }

  f32x4 oacc[4] = {};
  float mrun = -1e30f, lrun = 0.f;

  const bf16* Kbase = qkv + (size_t)b * T_ * QKV_S + C_ + (size_t)h * D_;
  const bf16* Vbase = Vt + (size_t)bh * D_ * T_;

  const int strow = tid >> 3;
  const int stswz = ((tid & 7) * 16) ^ ((strow & 7) << 4);
  const int rsw = (li & 7) << 4;

  auto stage = [&](int kv0, int bufi) __attribute__((always_inline)) {
    const bf16* gk = Kbase + (size_t)(kv0 + strow) * QKV_S + (stswz >> 1);
    const bf16* gv = Vbase + (size_t)strow * T_ + kv0 + (stswz >> 1);
    __builtin_amdgcn_global_load_lds((__attribute__((address_space(1))) void*)gk,
                                     (__attribute__((address_space(3))) void*)(&Ks[bufi][wid * 512]), 16, 0, 0);
    __builtin_amdgcn_global_load_lds((__attribute__((address_space(1))) void*)gv,
                                     (__attribute__((address_space(3))) void*)(&Vs[bufi][wid * 512]), 16, 0, 0);
  };

  auto compute = [&](int kv0, int bufi, bool masked) __attribute__((always_inline)) {
    const char* Kb = (const char*)&Ks[bufi][0];
    const char* Vb = (const char*)&Vs[bufi][0];

    f32x4 s[4] = {};
    __builtin_amdgcn_s_setprio(1);
#pragma unroll
    for (int n = 0; n < 4; ++n) {
      const char* kr = Kb + (n * 16 + li) * 128;
      bf16x8 kf0 = *reinterpret_cast<const bf16x8*>(kr + ((grp * 16) ^ rsw));
      bf16x8 kf1 = *reinterpret_cast<const bf16x8*>(kr + ((64 + grp * 16) ^ rsw));
      s[n] = __builtin_amdgcn_mfma_f32_16x16x32_bf16(kf0, qf[0], s[n], 0, 0, 0);
      s[n] = __builtin_amdgcn_mfma_f32_16x16x32_bf16(kf1, qf[1], s[n], 0, 0, 0);
    }
    __builtin_amdgcn_s_setprio(0);

    float p[4][4];
    float rm = -1e30f;
#pragma unroll
    for (int n = 0; n < 4; ++n)
#pragma unroll
      for (int j = 0; j < 4; ++j) {
        const int kv = kv0 + n * 16 + grp * 4 + j;
        float sv = fmaf(-slope, (float)(qi - kv), s[n][j]);
        if (masked) sv = (kv <= qi) ? sv : -1e30f;
        p[n][j] = sv;
        rm = fmaxf(rm, sv);
      }
    rm = fmaxf(rm, __shfl_xor(rm, 16, 64));
    rm = fmaxf(rm, __shfl_xor(rm, 32, 64));
    if (!__all(rm - mrun <= 8.0f)) {
      const float mnew = fmaxf(mrun, rm);
      const float alpha = __expf(mrun - mnew);
      mrun = mnew;
      lrun *= alpha;
#pragma unroll
      for (int nd = 0; nd < 4; ++nd)
#pragma unroll
        for (int j = 0; j < 4; ++j)
          oacc[nd][j] *= alpha;
    }
    float rs = 0.f;
#pragma unroll
    for (int n = 0; n < 4; ++n)
#pragma unroll
      for (int j = 0; j < 4; ++j) {
        float e = __expf(p[n][j] - mrun);
        p[n][j] = e;
        rs += e;
      }
    rs += __shfl_xor(rs, 16, 64);
    rs += __shfl_xor(rs, 32, 64);
    lrun += rs;

#pragma unroll
    for (int n = 0; n < 4; ++n) {
      bf16x4 p4;
#pragma unroll
      for (int j = 0; j < 4; ++j) p4[j] = (bf16)p[n][j];
      *reinterpret_cast<bf16x4*>(Pw + li * 72 + n * 16 + grp * 4) = p4;
    }
    asm volatile("s_waitcnt lgkmcnt(0)" ::: "memory");
    __builtin_amdgcn_sched_barrier(0);

    __builtin_amdgcn_s_setprio(1);
#pragma unroll
    for (int kc = 0; kc < 2; ++kc) {
      bf16x8 pb = *reinterpret_cast<const bf16x8*>(Pw + li * 72 + kc * 32 + grp * 8);
#pragma unroll
      for (int nd = 0; nd < 4; ++nd) {
        const char* vrp = Vb + (nd * 16 + li) * 128;
        bf16x8 vf = *reinterpret_cast<const bf16x8*>(vrp + ((kc * 64 + grp * 16) ^ rsw));
        oacc[nd] = __builtin_amdgcn_mfma_f32_16x16x32_bf16(vf, pb, oacc[nd], 0, 0, 0);
      }
    }
    __builtin_amdgcn_s_setprio(0);
  };

  const int nt = 2 * QT + 2;
  stage((nt - 1) * 64, 0);
  stage((nt - 2) * 64, 1);
  int r = 0;
  for (int t = 0; t < nt; ++t) {
    if (t + 1 < nt) asm volatile("s_waitcnt vmcnt(2)\ns_barrier" ::: "memory");
    else            asm volatile("s_waitcnt vmcnt(0)\ns_barrier" ::: "memory");
    if (t + 2 < nt) stage((nt - 3 - t) * 64, (r == 0) ? 2 : r - 1);
    const int kv0 = (nt - 1 - t) * 64;
    if (kv0 <= wq0) compute(kv0, r, kv0 + 64 > wq0);
    r = (r == 2) ? 0 : r + 1;
  }

  const float rinv = 1.f / lrun;
#pragma unroll
  for (int nd = 0; nd < 4; ++nd) {
    bf16x4 o4;
#pragma unroll
    for (int j = 0; j < 4; ++j) o4[j] = (bf16)(oacc[nd][j] * rinv);
    *reinterpret_cast<bf16x4*>(Pw + li * 72 + nd * 16 + grp * 4) = o4;
  }
  asm volatile("s_waitcnt lgkmcnt(0)" ::: "memory");
  __builtin_amdgcn_sched_barrier(0);
  {
    bf16* yrow = Y + (size_t)(b * T_ + qi) * C_ + h * D_;
#pragma unroll
    for (int c = 0; c < 2; ++c) {
      bf16x8 y8 = *reinterpret_cast<const bf16x8*>(Pw + li * 72 + (c * 4 + grp) * 8);
      *reinterpret_cast<bf16x8*>(yrow + (c * 4 + grp) * 8) = y8;
    }
  }
}

// ---------------------------------------------------------------- launch
extern "C" void kernel_launch(void* const* d_in, const int* in_sizes, int n_in,
                              void* d_out, int out_size, void* d_ws, size_t ws_size,
                              hipStream_t stream) {
  const float* x  = (const float*)d_in[0];
  const float* Wq = (const float*)d_in[1];
  const float* bq = (const float*)d_in[2];
  const float* Wk = (const float*)d_in[3];
  const float* bk = (const float*)d_in[4];
  const float* Wv = (const float*)d_in[5];
  const float* bv = (const float*)d_in[6];
  const float* Wo = (const float*)d_in[7];
  const float* bo = (const float*)d_in[8];
  float* out = (float*)d_out;

  char* ws = (char*)d_ws;
  bf16* xb    = (bf16*)ws; ws += (size_t)BT_ * C_ * 2;          // 8 MB (reused as yb)
  bf16* wqkvb = (bf16*)ws; ws += (size_t)3 * C_ * C_ * 2;       // 6 MB
  bf16* wob   = (bf16*)ws; ws += (size_t)C_ * C_ * 2;           // 2 MB
  bf16* qkvb  = (bf16*)ws; ws += (size_t)BT_ * QKV_S * 2;       // 24 MB (V third unused)
  bf16* vtb   = (bf16*)ws; ws += (size_t)B_ * H_ * D_ * T_ * 2; // 8 MB
  float* bqkv = (float*)ws; ws += (size_t)3 * C_ * 4;           // 12 KB
  bf16* yb    = xb;  // x dead after QKV GEMM

  {
    const int total = (BT_ * C_ + 4 * C_ * C_) / 4 + 768;
    cast_all<<<dim3((total + 255) / 256), dim3(256), 0, stream>>>(
        x, Wq, Wk, Wv, Wo, bq, bk, bv, xb, wqkvb, wob, bqkv);
  }

  // fused QKV projection: [BT,1024] @ [3072,1024]^T -> [BT,3072]; V part written transposed to vtb
  gemm_qkv<bf16, true><<<dim3(QKV_S / 256, BT_ / 128), dim3(256), 0, stream>>>(
      xb, wqkvb, bqkv, qkvb, vtb, BT_, QKV_S, C_);

  attn_kernel<<<dim3(T_ / 128, B_ * H_), dim3(512), 0, stream>>>(qkvb, vtb, yb);

  gemm_bt<float><<<dim3(C_ / 128, BT_ / 128), dim3(256), 0, stream>>>(
      yb, wob, bo, out, BT_, C_, C_);
}

// Round 11
// 208.206 us; speedup vs baseline: 1.2789x; 1.2789x over previous
//
#include <hip/hip_runtime.h>
#include <hip/hip_bf16.h>
#include <cstdint>
#include <cstddef>

#define B_ 2
#define T_ 2048
#define C_ 1024
#define H_ 16
#define D_ 64
#define BT_ (B_*T_)
#define QKV_S 3072

typedef __bf16 bf16;
typedef __bf16 bf16x4 __attribute__((ext_vector_type(4)));
typedef __bf16 bf16x8 __attribute__((ext_vector_type(8)));
typedef float f32x4 __attribute__((ext_vector_type(4)));

// ---------------------------------------------------------------- fused cast f32->bf16 (+ bias concat)
__global__ __launch_bounds__(256) void cast_all(const float* __restrict__ x,
                                                const float* __restrict__ wq,
                                                const float* __restrict__ wk,
                                                const float* __restrict__ wv,
                                                const float* __restrict__ wo,
                                                const float* __restrict__ bq,
                                                const float* __restrict__ bk,
                                                const float* __restrict__ bv,
                                                bf16* __restrict__ xb,
                                                bf16* __restrict__ wqkvb,
                                                bf16* __restrict__ wob,
                                                float* __restrict__ bqkv) {
  const int X4 = (BT_ * C_) / 4;     // 1048576
  const int W4 = (C_ * C_) / 4;      // 262144
  int i = blockIdx.x * blockDim.x + threadIdx.x;
  if (i >= X4 + 4 * W4 + 768) return;
  if (i >= X4 + 4 * W4) {
    int idx = i - (X4 + 4 * W4);        // 0..767 float4s
    int w = idx >> 8, off = idx & 255;
    const float* src = (w == 0) ? bq : (w == 1) ? bk : bv;
    reinterpret_cast<float4*>(bqkv + w * C_)[off] = reinterpret_cast<const float4*>(src)[off];
    return;
  }
  const float* src;
  bf16* dst;
  int off;
  if (i < X4) {
    src = x; dst = xb; off = i;
  } else {
    int k = i - X4;
    int w = k >> 18;        // /W4
    off = k & (W4 - 1);
    src = (w == 0) ? wq : (w == 1) ? wk : (w == 2) ? wv : wo;
    dst = (w < 3) ? (wqkvb + (size_t)w * C_ * C_) : wob;
  }
  float4 v = reinterpret_cast<const float4*>(src)[off];
  bf16x4 o;
  o[0] = (bf16)v.x; o[1] = (bf16)v.y; o[2] = (bf16)v.z; o[3] = (bf16)v.w;
  *reinterpret_cast<bf16x4*>(dst + (size_t)off * 4) = o;
}

// ---------------------------------------------------------------- GEMM (R7 version): 128x128, BK=32,
// 3-buffer depth-2 pipeline, counted vmcnt, one raw barrier per K-step.
// FUSE_VT: blocks with n0 >= 2048 write output transposed to VtOut[bh][d][t].
template<typename OutT, bool FUSE_VT>
__global__ __launch_bounds__(256) void gemm_bt(const bf16* __restrict__ A,
                                               const bf16* __restrict__ Bm,
                                               const float* __restrict__ bias,
                                               OutT* __restrict__ Cout,
                                               bf16* __restrict__ VtOut,
                                               int M, int N, int K) {
  __shared__ bf16 As[3][128 * 32];
  __shared__ bf16 Bs[3][128 * 32];
  const int tid = threadIdx.x;
  const int wid = tid >> 6, lane = tid & 63;
  const int grp = lane >> 4, li = lane & 15;
  const int wr = wid >> 1, wc = wid & 1;
  const int m0 = blockIdx.y * 128, n0 = blockIdx.x * 128;

  f32x4 acc[4][4] = {};

  const int srow = lane >> 2;         // 0..15
  const int scol = (lane & 3) * 8;    // 0,8,16,24

  auto stage = [&](int k0, int bufi) __attribute__((always_inline)) {
#pragma unroll
    for (int p = 0; p < 2; ++p) {
      const int rbase = (p * 4 + wid) * 16;
      const bf16* ga = A + (size_t)(m0 + rbase + srow) * K + (k0 + scol);
      const bf16* gb = Bm + (size_t)(n0 + rbase + srow) * K + (k0 + scol);
      __builtin_amdgcn_global_load_lds((__attribute__((address_space(1))) void*)ga,
                                       (__attribute__((address_space(3))) void*)(&As[bufi][(p * 4 + wid) * 512]), 16, 0, 0);
      __builtin_amdgcn_global_load_lds((__attribute__((address_space(1))) void*)gb,
                                       (__attribute__((address_space(3))) void*)(&Bs[bufi][(p * 4 + wid) * 512]), 16, 0, 0);
    }
  };

  const int nt = K >> 5;
  stage(0, 0);
  if (nt > 1) stage(32, 1);
  int r = 0;
  for (int t = 0; t < nt; ++t) {
    if (t + 1 < nt) asm volatile("s_waitcnt vmcnt(4)\ns_barrier" ::: "memory");
    else            asm volatile("s_waitcnt vmcnt(0)\ns_barrier" ::: "memory");
    if (t + 2 < nt) stage((t + 2) * 32, (r == 0) ? 2 : r - 1);

    bf16x8 af[4], bfr[4];
#pragma unroll
    for (int m = 0; m < 4; ++m)
      af[m] = *reinterpret_cast<const bf16x8*>(&As[r][(wr * 64 + m * 16 + li) * 32 + grp * 8]);
#pragma unroll
    for (int n = 0; n < 4; ++n)
      bfr[n] = *reinterpret_cast<const bf16x8*>(&Bs[r][(wc * 64 + n * 16 + li) * 32 + grp * 8]);
#pragma unroll
    for (int m = 0; m < 4; ++m)
#pragma unroll
      for (int n = 0; n < 4; ++n)
        acc[m][n] = __builtin_amdgcn_mfma_f32_16x16x32_bf16(af[m], bfr[n], acc[m][n], 0, 0, 0);

    r = (r == 2) ? 0 : r + 1;
  }

  float bcol[4];
#pragma unroll
  for (int n = 0; n < 4; ++n) bcol[n] = bias[n0 + wc * 64 + n * 16 + li];

  if (FUSE_VT && n0 >= 2 * C_) {
#pragma unroll
    for (int m = 0; m < 4; ++m) {
      const int row0 = m0 + wr * 64 + m * 16 + grp * 4;   // 4-aligned
      const int b = row0 >> 11, t = row0 & (T_ - 1);
#pragma unroll
      for (int n = 0; n < 4; ++n) {
        const int hd = (n0 - 2 * C_) + wc * 64 + n * 16 + li;
        bf16x4 o4;
#pragma unroll
        for (int j = 0; j < 4; ++j) o4[j] = (bf16)(acc[m][n][j] + bcol[n]);
        *reinterpret_cast<bf16x4*>(VtOut + ((size_t)(b * C_ + hd)) * T_ + t) = o4;
      }
    }
  } else {
#pragma unroll
    for (int m = 0; m < 4; ++m) {
#pragma unroll
      for (int n = 0; n < 4; ++n) {
        const int col = n0 + wc * 64 + n * 16 + li;
#pragma unroll
        for (int j = 0; j < 4; ++j) {
          const int row = m0 + wr * 64 + m * 16 + grp * 4 + j;
          float v = acc[m][n][j] + bcol[n];
          Cout[(size_t)row * N + col] = (OutT)v;
        }
      }
    }
  }
}

// ---------------------------------------------------------------- flash attention w/ ALiBi
// Constant-work pairing: block bx processes q-tiles {15-bx, bx} sequentially ->
// every block = exactly 34 kv-tiles; grid (8, B*H) = 256 blocks = 1 per CU (LDS 82 KB
// forces 1 block/CU). Per q-tile: swapped-operand S^T = K@Q^T, diagonal-first reversed
// kv order, defer-max, 3-of-4-buffer depth-2 pipeline with counted vmcnt + one raw
// barrier per tile. V fragments prefetched before softmax (independent of P).
__global__ __launch_bounds__(512) void attn_kernel(const bf16* __restrict__ qkv,
                                                   const bf16* __restrict__ Vt,
                                                   bf16* __restrict__ Y) {
  __shared__ bf16 Ks[4][64 * 64];   // 4th buffer = LDS pad to force 1 block/CU
  __shared__ bf16 Vs[4][64 * 64];
  __shared__ bf16 Ps[8 * 16 * 72];

  const int tid = threadIdx.x;
  const int wid = tid >> 6, lane = tid & 63;
  const int grp = lane >> 4, li = lane & 15;
  const int bh = blockIdx.y;
  const int b = bh >> 4, h = bh & 15;
  const float slope = exp2f(-0.5f * (float)(h + 1));

  bf16* Pw = Ps + wid * (16 * 72);

  const bf16* Kbase = qkv + (size_t)b * T_ * QKV_S + C_ + (size_t)h * D_;
  const bf16* Vbase = Vt + (size_t)bh * D_ * T_;

  const int strow = tid >> 3;
  const int stswz = ((tid & 7) * 16) ^ ((strow & 7) << 4);
  const int rsw = (li & 7) << 4;

  auto stage = [&](int kv0, int bufi) __attribute__((always_inline)) {
    const bf16* gk = Kbase + (size_t)(kv0 + strow) * QKV_S + (stswz >> 1);
    const bf16* gv = Vbase + (size_t)strow * T_ + kv0 + (stswz >> 1);
    __builtin_amdgcn_global_load_lds((__attribute__((address_space(1))) void*)gk,
                                     (__attribute__((address_space(3))) void*)(&Ks[bufi][wid * 512]), 16, 0, 0);
    __builtin_amdgcn_global_load_lds((__attribute__((address_space(1))) void*)gv,
                                     (__attribute__((address_space(3))) void*)(&Vs[bufi][wid * 512]), 16, 0, 0);
  };

  auto do_qtile = [&](int QT) __attribute__((always_inline)) {
    const int q0 = QT * 128;
    const int wq0 = q0 + wid * 16;
    const int qi = wq0 + li;

    // Q fragments (B-operand: row=li<->q, k=d), pre-scaled by 1/8 (exact in bf16)
    bf16x8 qf[2];
    {
      const bf16* qrow = qkv + (size_t)(b * T_ + qi) * QKV_S + h * D_;
      qf[0] = *reinterpret_cast<const bf16x8*>(qrow + grp * 8);
      qf[1] = *reinterpret_cast<const bf16x8*>(qrow + 32 + grp * 8);
#pragma unroll
      for (int c = 0; c < 2; ++c)
#pragma unroll
        for (int j = 0; j < 8; ++j)
          qf[c][j] = (bf16)((float)qf[c][j] * 0.125f);
    }

    f32x4 oacc[4] = {};      // O^T: [d = nd*16+grp*4+j][q = li]
    float mrun = -1e30f, lrun = 0.f;

    auto compute = [&](int kv0, int bufi, bool masked) __attribute__((always_inline)) {
      const char* Kb = (const char*)&Ks[bufi][0];
      const char* Vb = (const char*)&Vs[bufi][0];

      // S^T = K @ Q^T
      f32x4 s[4] = {};
      __builtin_amdgcn_s_setprio(1);
#pragma unroll
      for (int n = 0; n < 4; ++n) {
        const char* kr = Kb + (n * 16 + li) * 128;
        bf16x8 kf0 = *reinterpret_cast<const bf16x8*>(kr + ((grp * 16) ^ rsw));
        bf16x8 kf1 = *reinterpret_cast<const bf16x8*>(kr + ((64 + grp * 16) ^ rsw));
        s[n] = __builtin_amdgcn_mfma_f32_16x16x32_bf16(kf0, qf[0], s[n], 0, 0, 0);
        s[n] = __builtin_amdgcn_mfma_f32_16x16x32_bf16(kf1, qf[1], s[n], 0, 0, 0);
      }
      __builtin_amdgcn_s_setprio(0);

      // V fragment prefetch (independent of P) — overlaps the softmax VALU chain
      bf16x8 vr[2][4];
#pragma unroll
      for (int kc = 0; kc < 2; ++kc)
#pragma unroll
        for (int nd = 0; nd < 4; ++nd) {
          const char* vrp = Vb + (nd * 16 + li) * 128;
          vr[kc][nd] = *reinterpret_cast<const bf16x8*>(vrp + ((kc * 64 + grp * 16) ^ rsw));
        }

      // lane-local softmax over 16 kv regs; 2 shuffles per reduce
      float p[4][4];
      float rm = -1e30f;
#pragma unroll
      for (int n = 0; n < 4; ++n)
#pragma unroll
        for (int j = 0; j < 4; ++j) {
          const int kv = kv0 + n * 16 + grp * 4 + j;
          float sv = fmaf(-slope, (float)(qi - kv), s[n][j]);
          if (masked) sv = (kv <= qi) ? sv : -1e30f;
          p[n][j] = sv;
          rm = fmaxf(rm, sv);
        }
      rm = fmaxf(rm, __shfl_xor(rm, 16, 64));
      rm = fmaxf(rm, __shfl_xor(rm, 32, 64));
      if (!__all(rm - mrun <= 8.0f)) {   // T13 defer-max
        const float mnew = fmaxf(mrun, rm);
        const float alpha = __expf(mrun - mnew);
        mrun = mnew;
        lrun *= alpha;
#pragma unroll
        for (int nd = 0; nd < 4; ++nd)
#pragma unroll
          for (int j = 0; j < 4; ++j)
            oacc[nd][j] *= alpha;
      }
      float rs = 0.f;
#pragma unroll
      for (int n = 0; n < 4; ++n)
#pragma unroll
        for (int j = 0; j < 4; ++j) {
          float e = __expf(p[n][j] - mrun);
          p[n][j] = e;
          rs += e;
        }
      rs += __shfl_xor(rs, 16, 64);
      rs += __shfl_xor(rs, 32, 64);
      lrun += rs;

      // P relayout through per-wave LDS
#pragma unroll
      for (int n = 0; n < 4; ++n) {
        bf16x4 p4;
#pragma unroll
        for (int j = 0; j < 4; ++j) p4[j] = (bf16)p[n][j];
        *reinterpret_cast<bf16x4*>(Pw + li * 72 + n * 16 + grp * 4) = p4;
      }
      asm volatile("s_waitcnt lgkmcnt(0)" ::: "memory");
      __builtin_amdgcn_sched_barrier(0);

      // O^T += Vt-tile @ P^T (V already in regs)
      __builtin_amdgcn_s_setprio(1);
#pragma unroll
      for (int kc = 0; kc < 2; ++kc) {
        bf16x8 pb = *reinterpret_cast<const bf16x8*>(Pw + li * 72 + kc * 32 + grp * 8);
#pragma unroll
        for (int nd = 0; nd < 4; ++nd)
          oacc[nd] = __builtin_amdgcn_mfma_f32_16x16x32_bf16(vr[kc][nd], pb, oacc[nd], 0, 0, 0);
      }
      __builtin_amdgcn_s_setprio(0);
    };

    const int nt = 2 * QT + 2;
    // reversed tile order (diagonal first)
    stage((nt - 1) * 64, 0);
    stage((nt - 2) * 64, 1);
    int r = 0;
    for (int t = 0; t < nt; ++t) {
      if (t + 1 < nt) asm volatile("s_waitcnt vmcnt(2)\ns_barrier" ::: "memory");
      else            asm volatile("s_waitcnt vmcnt(0)\ns_barrier" ::: "memory");
      if (t + 2 < nt) stage((nt - 3 - t) * 64, (r == 0) ? 2 : r - 1);   // (r+2)%3
      const int kv0 = (nt - 1 - t) * 64;
      if (kv0 <= wq0) compute(kv0, r, kv0 + 64 > wq0);
      r = (r == 2) ? 0 : r + 1;
    }

    // epilogue: O^T/l -> transpose via Pw -> Y rows
    const float rinv = 1.f / lrun;
#pragma unroll
    for (int nd = 0; nd < 4; ++nd) {
      bf16x4 o4;
#pragma unroll
      for (int j = 0; j < 4; ++j) o4[j] = (bf16)(oacc[nd][j] * rinv);
      *reinterpret_cast<bf16x4*>(Pw + li * 72 + nd * 16 + grp * 4) = o4;
    }
    asm volatile("s_waitcnt lgkmcnt(0)" ::: "memory");
    __builtin_amdgcn_sched_barrier(0);
    {
      bf16* yrow = Y + (size_t)(b * T_ + qi) * C_ + h * D_;
#pragma unroll
      for (int c = 0; c < 2; ++c) {
        bf16x8 y8 = *reinterpret_cast<const bf16x8*>(Pw + li * 72 + (c * 4 + grp) * 8);
        *reinterpret_cast<bf16x8*>(yrow + (c * 4 + grp) * 8) = y8;
      }
    }
    __syncthreads();   // all waves done with Ks/Vs before next q-tile restages
  };

  do_qtile(15 - (int)blockIdx.x);   // heavy half first
  do_qtile((int)blockIdx.x);        // light half — constant 34 tiles per block total
}

// ---------------------------------------------------------------- launch
extern "C" void kernel_launch(void* const* d_in, const int* in_sizes, int n_in,
                              void* d_out, int out_size, void* d_ws, size_t ws_size,
                              hipStream_t stream) {
  const float* x  = (const float*)d_in[0];
  const float* Wq = (const float*)d_in[1];
  const float* bq = (const float*)d_in[2];
  const float* Wk = (const float*)d_in[3];
  const float* bk = (const float*)d_in[4];
  const float* Wv = (const float*)d_in[5];
  const float* bv = (const float*)d_in[6];
  const float* Wo = (const float*)d_in[7];
  const float* bo = (const float*)d_in[8];
  float* out = (float*)d_out;

  char* ws = (char*)d_ws;
  bf16* xb    = (bf16*)ws; ws += (size_t)BT_ * C_ * 2;          // 8 MB (reused as yb)
  bf16* wqkvb = (bf16*)ws; ws += (size_t)3 * C_ * C_ * 2;       // 6 MB
  bf16* wob   = (bf16*)ws; ws += (size_t)C_ * C_ * 2;           // 2 MB
  bf16* qkvb  = (bf16*)ws; ws += (size_t)BT_ * QKV_S * 2;       // 24 MB (V third unused)
  bf16* vtb   = (bf16*)ws; ws += (size_t)B_ * H_ * D_ * T_ * 2; // 8 MB
  float* bqkv = (float*)ws; ws += (size_t)3 * C_ * 4;           // 12 KB
  bf16* yb    = xb;  // x dead after QKV GEMM

  {
    const int total = (BT_ * C_ + 4 * C_ * C_) / 4 + 768;
    cast_all<<<dim3((total + 255) / 256), dim3(256), 0, stream>>>(
        x, Wq, Wk, Wv, Wo, bq, bk, bv, xb, wqkvb, wob, bqkv);
  }

  // fused QKV projection: [BT,1024] @ [3072,1024]^T -> [BT,3072]; V part written transposed to vtb
  gemm_bt<bf16, true><<<dim3(QKV_S / 128, BT_ / 128), dim3(256), 0, stream>>>(
      xb, wqkvb, bqkv, qkvb, vtb, BT_, QKV_S, C_);

  attn_kernel<<<dim3(8, B_ * H_), dim3(512), 0, stream>>>(qkvb, vtb, yb);

  gemm_bt<float, false><<<dim3(C_ / 128, BT_ / 128), dim3(256), 0, stream>>>(
      yb, wob, bo, out, nullptr, BT_, C_, C_);
}